// Round 6
// baseline (360.833 us; speedup 1.0000x reference)
//
#include <hip/hip_runtime.h>

// PRCutBatchLoss: total = sum_{a,b,k} W[a,b]*(Pl[a,k]+Pr[b,k]-2*Pl[a,k]*Pr[b,k])/cp[k]
// One streaming pass over W (256 MiB fp32):
//   total = sum_{a,b} W[a,b] * ( la[a] + rs[b] + sum_k q[a,k]*pr'[b,k] )
// with pr'[b,k]=Pr[b,k]/cp[k], rs[b]=sum_k pr'[b,k],
//      la[a]=sum_k Pl[a,k]/cp[k], q[a,k] = -2*Pl[a,k].
//
// R6 vs R5 — remove the suspects shared by the (identical-scoring) R4 and R5:
//  (a) PLAIN float4 W loads (drop nontemporal). Every measured 6+ TB/s
//      datapoint on this box (harness fills, m13 copy) uses plain accesses.
//  (b) Perfect-fill grid: 512 blocks x 512 thr = EXACTLY 2 blocks/CU, no
//      partial second round (R4/R5's 1024 blocks at 2-3/CU left a low-MLP
//      tail round worth up to ~25%). Tile = 2048 cols x 64 rows.
//  (c) __launch_bounds__(512,4) -> 128-VGPR cap; live set ~75 -> zero spill
//      risk (R5 sat at an 85 cap with ~80 live).
//  (d) P=4 rolling prefetch: 16 waves/CU x 4 KB = 64 KB in flight per CU,
//      ~6x the Little's-law requirement at 6.7 TB/s.

constexpr int K     = 10;    // clusters (fixed by problem)
constexpr int REC   = 12;    // per-row record: [la, q0..q9, pad] (48 B)
constexpr int TM    = 64;    // rows per block tile
constexpr int BLOCK = 512;   // threads per block
constexpr int COLS  = BLOCK * 4;  // 2048 contiguous columns per block
constexpr int P     = 4;     // prefetch depth (rows in flight per thread)

typedef float f4 __attribute__((ext_vector_type(4)));

// Fold Pl/cp into per-row records; also zero the output accumulator.
__global__ void prcut_prep(const float* __restrict__ Pl,
                           const float* __restrict__ cp,
                           float* __restrict__ rec,
                           float* __restrict__ out, int A)
{
    const int a = blockIdx.x * blockDim.x + threadIdx.x;
    if (a == 0) out[0] = 0.0f;
    if (a >= A) return;
    float la = 0.0f;
    float r[REC];
#pragma unroll
    for (int k = 0; k < K; ++k) {
        const float p = Pl[(size_t)a * K + k];
        la = fmaf(p, 1.0f / cp[k], la);
        r[1 + k] = -2.0f * p;
    }
    r[0]  = la;
    r[11] = 0.0f;
#pragma unroll
    for (int k = 0; k < REC; ++k) rec[(size_t)a * REC + k] = r[k];
}

__global__ __launch_bounds__(BLOCK, 4) void prcut_main(
    const float* __restrict__ W,
    const float* __restrict__ Pr,
    const float* __restrict__ cp,
    const float* __restrict__ rec,
    float* __restrict__ out,
    int Bn)
{
    // --- Stage this 64-row band's records into LDS (one-time) ---
    __shared__ f4 lrec[TM * REC / 4];          // 192 x f4 = 3 KB
    const int t  = threadIdx.x;
    const int a0 = blockIdx.y * TM;
    for (int i = t; i < TM * REC; i += BLOCK)
        ((float*)lrec)[i] = rec[(size_t)a0 * REC + i];

    // --- Register-stationary scaled pr' for this thread's 4 columns ---
    const int c0 = blockIdx.x * COLS + t * 4;
    float pr[4][K];
    float rs[4];
#pragma unroll
    for (int j = 0; j < 4; ++j) {
        const float* p = Pr + (size_t)(c0 + j) * K;
        float s = 0.0f;
#pragma unroll
        for (int k = 0; k < K; ++k) {
            const float v = p[k] * (1.0f / cp[k]);
            pr[j][k] = v;
            s += v;
        }
        rs[j] = s;
    }
    __syncthreads();

    // --- W pipeline: plain loads, vmcnt carries ONLY these ---
    const float* wp  = W + (size_t)a0 * Bn + c0;
    const float* wld = wp + (size_t)P * Bn;

    f4 wbuf[P];
#pragma unroll
    for (int i = 0; i < P; ++i)
        wbuf[i] = *reinterpret_cast<const f4*>(wp + (size_t)i * Bn);

    float acc = 0.0f;

#pragma unroll 4
    for (int r = 0; r < TM - P; ++r) {
        // Broadcast row coefficients from LDS (uniform address -> free).
        const f4 qa = lrec[r * 3 + 0];   // {la, q0, q1, q2}
        const f4 qb = lrec[r * 3 + 1];   // {q3, q4, q5, q6}
        const f4 qc = lrec[r * 3 + 2];   // {q7, q8, q9, 0}
        const float la = qa.x;
        const float qv[K] = {qa.y, qa.z, qa.w, qb.x, qb.y,
                             qb.z, qb.w, qc.x, qc.y, qc.z};

        float d[4];
#pragma unroll
        for (int j = 0; j < 4; ++j) d[j] = la + rs[j];
#pragma unroll
        for (int k = 0; k < K; ++k) {
#pragma unroll
            for (int j = 0; j < 4; ++j) d[j] = fmaf(qv[k], pr[j][k], d[j]);
        }

        const int slot = r & (P - 1);
        const f4 w = wbuf[slot];                    // waits vmcnt(P-1) only
        wbuf[slot] = *reinterpret_cast<const f4*>(wld);
        wld += Bn;

        acc = fmaf(w.x, d[0], acc);
        acc = fmaf(w.y, d[1], acc);
        acc = fmaf(w.z, d[2], acc);
        acc = fmaf(w.w, d[3], acc);
    }

    // Drain the last P rows (no further prefetch).
#pragma unroll
    for (int r = TM - P; r < TM; ++r) {
        const f4 qa = lrec[r * 3 + 0];
        const f4 qb = lrec[r * 3 + 1];
        const f4 qc = lrec[r * 3 + 2];
        const float la = qa.x;
        const float qv[K] = {qa.y, qa.z, qa.w, qb.x, qb.y,
                             qb.z, qb.w, qc.x, qc.y, qc.z};

        float d[4];
#pragma unroll
        for (int j = 0; j < 4; ++j) d[j] = la + rs[j];
#pragma unroll
        for (int k = 0; k < K; ++k) {
#pragma unroll
            for (int j = 0; j < 4; ++j) d[j] = fmaf(qv[k], pr[j][k], d[j]);
        }

        const f4 w = wbuf[r & (P - 1)];
        acc = fmaf(w.x, d[0], acc);
        acc = fmaf(w.y, d[1], acc);
        acc = fmaf(w.z, d[2], acc);
        acc = fmaf(w.w, d[3], acc);
    }

    // wave(64) shuffle reduction -> LDS -> one atomic per block
#pragma unroll
    for (int off = 32; off > 0; off >>= 1)
        acc += __shfl_down(acc, off, 64);

    __shared__ float wsum[BLOCK / 64];
    const int lane = t & 63;
    const int wid  = t >> 6;
    if (lane == 0) wsum[wid] = acc;
    __syncthreads();

    if (t == 0) {
        float s = 0.0f;
#pragma unroll
        for (int i = 0; i < BLOCK / 64; ++i) s += wsum[i];
        atomicAdd(out, s);  // device-scope: cross-XCD safe; 512 total
    }
}

extern "C" void kernel_launch(void* const* d_in, const int* in_sizes, int n_in,
                              void* d_out, int out_size, void* d_ws, size_t ws_size,
                              hipStream_t stream) {
    const float* W  = (const float*)d_in[0];
    const float* Pl = (const float*)d_in[1];
    const float* Pr = (const float*)d_in[2];
    const float* cp = (const float*)d_in[3];
    float* out = (float*)d_out;
    float* rec = (float*)d_ws;           // 8192*12*4 B = 384 KB of scratch

    const int Kn = in_sizes[3];          // 10
    const int A  = in_sizes[1] / Kn;     // 8192
    const int B  = in_sizes[2] / Kn;     // 8192

    // Fold Pl -> [la, q0..q9] records; zero d_out (poisoned every call).
    prcut_prep<<<(A + 255) / 256, 256, 0, stream>>>(Pl, cp, rec, out, A);

    dim3 grid(B / COLS, A / TM);         // 4 x 128 = 512 blocks = 2/CU exact
    prcut_main<<<grid, BLOCK, 0, stream>>>(W, Pr, cp, rec, out, B);
}